// Round 8
// baseline (205.633 us; speedup 1.0000x reference)
//
#include <hip/hip_runtime.h>
#include <math.h>

#define BB 128
#define MM 200
#define SS 20
#define DD 128
#define NCC 10000
#define CL 10
#define LCT 64

__device__ __forceinline__ unsigned pack_bf16(float a, float b) {
    unsigned ua = __float_as_uint(a), ub = __float_as_uint(b);
    ua += 0x7fff + ((ua >> 16) & 1);  // RNE; inputs finite
    ub += 0x7fff + ((ub >> 16) & 1);
    return (ua >> 16) | (ub & 0xffff0000u);
}
__device__ __forceinline__ float bflo(unsigned v) { return __uint_as_float(v << 16); }
__device__ __forceinline__ float bfhi(unsigned v) { return __uint_as_float(v & 0xffff0000u); }

// int64-vs-int32 detection from 8 broadcast words of queries (odd words are the
// all-zero high halves iff int64; for int32 they're tokens, P(zero)=1e-5 each).
__device__ __forceinline__ int detect_shift(const int* __restrict__ q) {
    int zc = 0;
#pragma unroll
    for (int i = 0; i < 8; ++i) zc += (q[2 * i + 1] == 0);
    return (zc >= 6) ? 1 : 0;
}

// All random gathers in one chip-wide dispatch (512 blocks x 512 threads) for
// maximum outstanding HBM misses. Stories -> m_ws (packed bf16), candidates ->
// cand_ws (f32), queries -> u_ws (f32). Direct from f32 tables (no conv pass).
__global__ __launch_bounds__(512) void k_gather(const int* __restrict__ stories,
                                                const int* __restrict__ queries,
                                                const int* __restrict__ cands,
                                                const float* __restrict__ A,
                                                const float* __restrict__ W,
                                                unsigned* __restrict__ m_ws,
                                                float* __restrict__ cand_ws,
                                                float* __restrict__ u_ws) {
    int gid = blockIdx.x, tid = threadIdx.x;
    int shift = detect_shift(queries);
    int g = tid >> 5, l = tid & 31;

    // Stories: 50 rows per block (row = b*MM + mm), 16 groups x 32 lanes.
    int base = gid * 50;
#pragma unroll
    for (int r = 0; r < 4; ++r) {
        int rl = (r << 4) + g;
        if (rl < 50) {
            int row = base + rl;
            int toks[SS];
#pragma unroll
            for (int s = 0; s < SS; ++s)
                toks[s] = stories[((size_t)(row * SS + s)) << shift];
            float4 acc = make_float4(0.f, 0.f, 0.f, 0.f);
#pragma unroll
            for (int s = 0; s < SS; ++s) {
                float4 v = ((const float4*)(A + (size_t)toks[s] * DD))[l];
                float msk = toks[s] ? 1.f : 0.f;  // padding row 0
                acc.x = fmaf(msk, v.x, acc.x);
                acc.y = fmaf(msk, v.y, acc.y);
                acc.z = fmaf(msk, v.z, acc.z);
                acc.w = fmaf(msk, v.w, acc.w);
            }
            uint2 o;
            o.x = pack_bf16(acc.x, acc.y);
            o.y = pack_bf16(acc.z, acc.w);
            ((uint2*)(m_ws + (size_t)row * (DD / 2)))[l] = o;
        }
    }
    // Candidates: 20 rows per block (f32 out, masked).
#pragma unroll
    for (int r = 0; r < 2; ++r) {
        int rl = (r << 4) + g;
        int row = gid * 20 + rl;
        if (rl < 20 && row < NCC) {
            int toks[CL];
#pragma unroll
            for (int s = 0; s < CL; ++s)
                toks[s] = cands[((size_t)(row * CL + s)) << shift];
            float4 acc = make_float4(0.f, 0.f, 0.f, 0.f);
#pragma unroll
            for (int s = 0; s < CL; ++s) {
                float4 v = ((const float4*)(W + (size_t)toks[s] * DD))[l];
                float msk = toks[s] ? 1.f : 0.f;
                acc.x = fmaf(msk, v.x, acc.x);
                acc.y = fmaf(msk, v.y, acc.y);
                acc.z = fmaf(msk, v.z, acc.z);
                acc.w = fmaf(msk, v.w, acc.w);
            }
            ((float4*)(cand_ws + (size_t)row * DD))[l] = acc;
        }
    }
    // Queries: block b < 128, 32 lanes, f32 sum (exact).
    if (gid < BB && tid < 32) {
        int toks[SS];
#pragma unroll
        for (int s = 0; s < SS; ++s)
            toks[s] = queries[((size_t)(gid * SS + s)) << shift];
        float4 acc = make_float4(0.f, 0.f, 0.f, 0.f);
#pragma unroll
        for (int s = 0; s < SS; ++s) {
            float4 v = ((const float4*)(A + (size_t)toks[s] * DD))[tid];
            float msk = toks[s] ? 1.f : 0.f;
            acc.x = fmaf(msk, v.x, acc.x);
            acc.y = fmaf(msk, v.y, acc.y);
            acc.z = fmaf(msk, v.z, acc.z);
            acc.w = fmaf(msk, v.w, acc.w);
        }
        ((float4*)(u_ws + (size_t)gid * DD))[tid] = acc;
    }
}

// 3 fused hops, one block per batch, m read from L2-warm m_ws (coalesced
// 256B-per-row wave reads) — only 5.6 KB LDS, no staging cliff.
__global__ __launch_bounds__(512) void k_hops(const unsigned* __restrict__ m_ws,
                                              const float* __restrict__ u_ws,
                                              const float* __restrict__ Hw,
                                              float* __restrict__ uT) {
    __shared__ float u_s[DD];
    __shared__ float p_s[MM];
    __shared__ float o_part[8][DD];
    __shared__ float red_s;
    int b = blockIdx.x, tid = threadIdx.x;
    int wave = tid >> 6, lane = tid & 63;
    const unsigned* mb = m_ws + (size_t)b * MM * (DD / 2);

    if (tid < DD) u_s[tid] = u_ws[b * DD + tid];
    __syncthreads();

    for (int hop = 0; hop < 3; ++hop) {
        // Phase 1: p[mm] = m[mm,:] . u — wave per row (25 rows/wave), lane j
        // reads uint j of the row (256B coalesced), 6-level shuffle reduce.
        {
            float2 uu = ((const float2*)u_s)[lane];
            for (int i = 0; i < 25; ++i) {
                int mm = wave * 25 + i;
                unsigned pv = mb[mm * (DD / 2) + lane];
                float d = bflo(pv) * uu.x + bfhi(pv) * uu.y;
                for (int off = 32; off; off >>= 1) d += __shfl_down(d, off);
                if (lane == 0) p_s[mm] = d;
            }
        }
        __syncthreads();
        // Softmax over 200 (wave 0; 1/sum deferred to phase 3)
        if (tid < 64) {
            float v0 = p_s[tid], v1 = p_s[tid + 64], v2 = p_s[tid + 128];
            float v3 = (tid < 8) ? p_s[tid + 192] : -1e30f;
            float mx = fmaxf(fmaxf(v0, v1), fmaxf(v2, v3));
            for (int off = 32; off; off >>= 1) mx = fmaxf(mx, __shfl_down(mx, off));
            mx = __shfl(mx, 0);
            float e0 = __expf(v0 - mx), e1 = __expf(v1 - mx), e2 = __expf(v2 - mx);
            float e3 = (tid < 8) ? __expf(v3 - mx) : 0.f;
            float sm = e0 + e1 + e2 + e3;
            for (int off = 32; off; off >>= 1) sm += __shfl_down(sm, off);
            p_s[tid] = e0;
            p_s[tid + 64] = e1;
            p_s[tid + 128] = e2;
            if (tid < 8) p_s[tid + 192] = e3;
            if (tid == 0) red_s = 1.f / __shfl(sm, 0);
        }
        __syncthreads();
        // Phase 2: o[d] = sum_mm e[mm]*m[mm,d] — wave h covers mm h*25..+24,
        // lane c reads uint c of each row (coalesced), p broadcast.
        {
            int c = tid & 63, h = tid >> 6;
            int mm0 = h * 25;
            float ax = 0.f, ay = 0.f;
#pragma unroll 5
            for (int k = 0; k < 25; ++k) {
                unsigned pv = mb[(mm0 + k) * (DD / 2) + c];
                float p = p_s[mm0 + k];
                ax = fmaf(p, bflo(pv), ax);
                ay = fmaf(p, bfhi(pv), ay);
            }
            o_part[h][2 * c] = ax;
            o_part[h][2 * c + 1] = ay;
        }
        __syncthreads();
        // Phase 3: u'[d] = tanh( Hw[d,:] . u + inv * o[d] )
        float u_new = 0.f;
        if (tid < DD) {
            float o = 0.f;
#pragma unroll
            for (int h = 0; h < 8; ++h) o += o_part[h][tid];
            float acc = o * red_s;
            const float4* hrow = (const float4*)(Hw + tid * DD);
            const float4* u4 = (const float4*)u_s;
#pragma unroll 8
            for (int j = 0; j < DD / 4; ++j) {
                float4 hv = hrow[j];
                float4 uv = u4[j];
                acc += hv.x * uv.x + hv.y * uv.y + hv.z * uv.z + hv.w * uv.w;
            }
            u_new = tanhf(acc);
        }
        __syncthreads();
        if (tid < DD) u_s[tid] = u_new;
        __syncthreads();
    }
    if (tid < DD) uT[tid * BB + b] = u_s[tid];
}

// logits[b,c] = u[b,:] . cand_sum[c,:]. Block = 128 batches x 64 cands,
// 256 threads; thread = 4-batch x 8-cand register tile; k-major LDS cand tile.
__global__ __launch_bounds__(256) void k_logits(const float* __restrict__ uT,
                                                const float* __restrict__ cs,
                                                float* __restrict__ out) {
    __shared__ float c_s[DD][LCT + 4];  // 34.8 KB
    int c0 = blockIdx.x * LCT;
    int tid = threadIdx.x;
    {
        int c = tid >> 2, l = tid & 3;  // c 0..63, l = k-quarter
        int row = c0 + c;
        if (row >= NCC) row = NCC - 1;
        const float4* rp = (const float4*)(cs + (size_t)row * DD);
#pragma unroll
        for (int i = 0; i < 8; ++i) {
            int k = (l << 5) + (i << 2);
            float4 v = rp[(l << 3) + i];
            c_s[k][c] = v.x;
            c_s[k + 1][c] = v.y;
            c_s[k + 2][c] = v.z;
            c_s[k + 3][c] = v.w;
        }
    }
    __syncthreads();
    int tx = tid & 31, ty = tid >> 5;  // tx: 4 batches, ty: 8 cands
    const float* cb = &c_s[0][ty << 3];
    const float4* up = (const float4*)(uT + (tx << 2));
    float acc[4][8];
#pragma unroll
    for (int i = 0; i < 4; ++i)
#pragma unroll
        for (int j = 0; j < 8; ++j) acc[i][j] = 0.f;
#pragma unroll 4
    for (int k = 0; k < DD; ++k) {
        float4 uv = up[k * (BB / 4)];
        float4 ca = *(const float4*)(cb + k * (LCT + 4));
        float4 cc = *(const float4*)(cb + k * (LCT + 4) + 4);
        float uu[4] = {uv.x, uv.y, uv.z, uv.w};
        float cv[8] = {ca.x, ca.y, ca.z, ca.w, cc.x, cc.y, cc.z, cc.w};
#pragma unroll
        for (int i = 0; i < 4; ++i)
#pragma unroll
            for (int j = 0; j < 8; ++j) acc[i][j] = fmaf(uu[i], cv[j], acc[i][j]);
    }
    if (c0 + (ty << 3) < NCC) {  // 8-chunks; NCC % 8 == 0
#pragma unroll
        for (int i = 0; i < 4; ++i) {
            float* orow = out + (size_t)((tx << 2) + i) * NCC + c0 + (ty << 3);
            ((float4*)orow)[0] = make_float4(acc[i][0], acc[i][1], acc[i][2], acc[i][3]);
            ((float4*)orow)[1] = make_float4(acc[i][4], acc[i][5], acc[i][6], acc[i][7]);
        }
    }
}

extern "C" void kernel_launch(void* const* d_in, const int* in_sizes, int n_in,
                              void* d_out, int out_size, void* d_ws, size_t ws_size,
                              hipStream_t stream) {
    const int* stories = (const int*)d_in[0];       // [128,200,20] tokens
    const int* queries = (const int*)d_in[1];       // [128,20]
    const int* cands   = (const int*)d_in[2];       // [10000,10]
    const float* A  = (const float*)d_in[3];        // f32 [100000,128]
    const float* W  = (const float*)d_in[4];        // f32 [100000,128]
    const float* Hw = (const float*)d_in[5];        // f32 [128,128]
    float* out = (float*)d_out;                     // f32 [128,10000]

    unsigned* m_ws = (unsigned*)d_ws;                             // 6.55 MB
    float* cand_ws = (float*)(m_ws + (size_t)BB * MM * (DD / 2)); // 5.12 MB
    float* u_ws = cand_ws + (size_t)NCC * DD;                     // 64 KB
    float* uT = u_ws + BB * DD;                                   // 64 KB

    k_gather<<<512, 512, 0, stream>>>(stories, queries, cands, A, W,
                                      m_ws, cand_ws, u_ws);
    k_hops<<<BB, 512, 0, stream>>>(m_ws, u_ws, Hw, uT);
    k_logits<<<(NCC + LCT - 1) / LCT, 256, 0, stream>>>(uT, cand_ws, out);
}

// Round 9
// 194.898 us; speedup vs baseline: 1.0551x; 1.0551x over previous
//
#include <hip/hip_runtime.h>
#include <math.h>

#define BB 128
#define MM 200
#define SS 20
#define DD 128
#define NCC 10000
#define CL 10
#define LCT 64

__device__ __forceinline__ unsigned pack_bf16(float a, float b) {
    unsigned ua = __float_as_uint(a), ub = __float_as_uint(b);
    ua += 0x7fff + ((ua >> 16) & 1);  // RNE; inputs finite
    ub += 0x7fff + ((ub >> 16) & 1);
    return (ua >> 16) | (ub & 0xffff0000u);
}
__device__ __forceinline__ float bflo(unsigned v) { return __uint_as_float(v << 16); }
__device__ __forceinline__ float bfhi(unsigned v) { return __uint_as_float(v & 0xffff0000u); }

// int64-vs-int32 detection from 8 broadcast words of queries (odd words are the
// all-zero high halves iff int64; for int32 they're tokens, P(zero)=1e-5 each).
__device__ __forceinline__ int detect_shift(const int* __restrict__ q) {
    int zc = 0;
#pragma unroll
    for (int i = 0; i < 8; ++i) zc += (q[2 * i + 1] == 0);
    return (zc >= 6) ? 1 : 0;
}

// All random gathers in one chip-wide dispatch (512 blocks x 512 threads).
// Explicit load arrays keep ~20 float4 gathers in flight per lane (VGPR-fat on
// purpose: R8's VGPR=36 build serialized the miss stream at 3.2 TB/s).
__global__ __launch_bounds__(512) void k_gather(const int* __restrict__ stories,
                                                const int* __restrict__ queries,
                                                const int* __restrict__ cands,
                                                const float* __restrict__ A,
                                                const float* __restrict__ W,
                                                unsigned* __restrict__ m_ws,
                                                float* __restrict__ cand_ws,
                                                float* __restrict__ u_ws) {
    int gid = blockIdx.x, tid = threadIdx.x;
    int shift = detect_shift(queries);
    int g = tid >> 5, l = tid & 31;

    // Stories: 50 rows per block (row = b*MM + mm), 16 groups x 32 lanes.
    int base = gid * 50;
#pragma unroll
    for (int r = 0; r < 4; ++r) {
        int rl = (r << 4) + g;
        if (rl < 50) {
            int row = base + rl;
            int toks[SS];
#pragma unroll
            for (int s = 0; s < SS; ++s)
                toks[s] = stories[((size_t)(row * SS + s)) << shift];
            float4 vv[SS];
#pragma unroll
            for (int s = 0; s < SS; ++s)
                vv[s] = ((const float4*)(A + (size_t)toks[s] * DD))[l];
            float4 acc = make_float4(0.f, 0.f, 0.f, 0.f);
#pragma unroll
            for (int s = 0; s < SS; ++s) {
                float msk = toks[s] ? 1.f : 0.f;  // padding row 0
                acc.x = fmaf(msk, vv[s].x, acc.x);
                acc.y = fmaf(msk, vv[s].y, acc.y);
                acc.z = fmaf(msk, vv[s].z, acc.z);
                acc.w = fmaf(msk, vv[s].w, acc.w);
            }
            uint2 o;
            o.x = pack_bf16(acc.x, acc.y);
            o.y = pack_bf16(acc.z, acc.w);
            ((uint2*)(m_ws + (size_t)row * (DD / 2)))[l] = o;
        }
    }
    // Candidates: 20 rows per block (f32 out, masked), 10 loads in flight.
#pragma unroll
    for (int r = 0; r < 2; ++r) {
        int rl = (r << 4) + g;
        int row = gid * 20 + rl;
        if (rl < 20 && row < NCC) {
            int toks[CL];
#pragma unroll
            for (int s = 0; s < CL; ++s)
                toks[s] = cands[((size_t)(row * CL + s)) << shift];
            float4 vv[CL];
#pragma unroll
            for (int s = 0; s < CL; ++s)
                vv[s] = ((const float4*)(W + (size_t)toks[s] * DD))[l];
            float4 acc = make_float4(0.f, 0.f, 0.f, 0.f);
#pragma unroll
            for (int s = 0; s < CL; ++s) {
                float msk = toks[s] ? 1.f : 0.f;
                acc.x = fmaf(msk, vv[s].x, acc.x);
                acc.y = fmaf(msk, vv[s].y, acc.y);
                acc.z = fmaf(msk, vv[s].z, acc.z);
                acc.w = fmaf(msk, vv[s].w, acc.w);
            }
            ((float4*)(cand_ws + (size_t)row * DD))[l] = acc;
        }
    }
    // Queries: block b < 128, 32 lanes, f32 sum (exact).
    if (gid < BB && tid < 32) {
        int toks[SS];
#pragma unroll
        for (int s = 0; s < SS; ++s)
            toks[s] = queries[((size_t)(gid * SS + s)) << shift];
        float4 vv[SS];
#pragma unroll
        for (int s = 0; s < SS; ++s)
            vv[s] = ((const float4*)(A + (size_t)toks[s] * DD))[tid];
        float4 acc = make_float4(0.f, 0.f, 0.f, 0.f);
#pragma unroll
        for (int s = 0; s < SS; ++s) {
            float msk = toks[s] ? 1.f : 0.f;
            acc.x = fmaf(msk, vv[s].x, acc.x);
            acc.y = fmaf(msk, vv[s].y, acc.y);
            acc.z = fmaf(msk, vv[s].z, acc.z);
            acc.w = fmaf(msk, vv[s].w, acc.w);
        }
        ((float4*)(u_ws + (size_t)gid * DD))[tid] = acc;
    }
}

// 3 fused hops, one block per batch, m read from L2-warm m_ws (coalesced
// 256B-per-row wave reads). Phase 1 runs 5 interleaved shuffle chains.
__global__ __launch_bounds__(512) void k_hops(const unsigned* __restrict__ m_ws,
                                              const float* __restrict__ u_ws,
                                              const float* __restrict__ Hw,
                                              float* __restrict__ uT) {
    __shared__ float u_s[DD];
    __shared__ float p_s[MM];
    __shared__ float o_part[8][DD];
    __shared__ float red_s;
    int b = blockIdx.x, tid = threadIdx.x;
    int wave = tid >> 6, lane = tid & 63;
    const unsigned* mb = m_ws + (size_t)b * MM * (DD / 2);

    if (tid < DD) u_s[tid] = u_ws[b * DD + tid];
    __syncthreads();

    for (int hop = 0; hop < 3; ++hop) {
        // Phase 1: p[mm] = m[mm,:] . u — wave per 25 rows, 5 rows per pass
        // (5 independent loads + 5 interleaved 6-level shuffle reductions).
        {
            float2 uu = ((const float2*)u_s)[lane];
#pragma unroll
            for (int i = 0; i < 5; ++i) {
                int mm0 = wave * 25 + i * 5;
                unsigned pv[5];
#pragma unroll
                for (int k = 0; k < 5; ++k)
                    pv[k] = mb[(mm0 + k) * (DD / 2) + lane];
                float d[5];
#pragma unroll
                for (int k = 0; k < 5; ++k)
                    d[k] = bflo(pv[k]) * uu.x + bfhi(pv[k]) * uu.y;
#pragma unroll
                for (int off = 32; off; off >>= 1)
#pragma unroll
                    for (int k = 0; k < 5; ++k) d[k] += __shfl_down(d[k], off);
                if (lane == 0) {
#pragma unroll
                    for (int k = 0; k < 5; ++k) p_s[mm0 + k] = d[k];
                }
            }
        }
        __syncthreads();
        // Softmax over 200 (wave 0; 1/sum deferred to phase 3)
        if (tid < 64) {
            float v0 = p_s[tid], v1 = p_s[tid + 64], v2 = p_s[tid + 128];
            float v3 = (tid < 8) ? p_s[tid + 192] : -1e30f;
            float mx = fmaxf(fmaxf(v0, v1), fmaxf(v2, v3));
            for (int off = 32; off; off >>= 1) mx = fmaxf(mx, __shfl_down(mx, off));
            mx = __shfl(mx, 0);
            float e0 = __expf(v0 - mx), e1 = __expf(v1 - mx), e2 = __expf(v2 - mx);
            float e3 = (tid < 8) ? __expf(v3 - mx) : 0.f;
            float sm = e0 + e1 + e2 + e3;
            for (int off = 32; off; off >>= 1) sm += __shfl_down(sm, off);
            p_s[tid] = e0;
            p_s[tid + 64] = e1;
            p_s[tid + 128] = e2;
            if (tid < 8) p_s[tid + 192] = e3;
            if (tid == 0) red_s = 1.f / __shfl(sm, 0);
        }
        __syncthreads();
        // Phase 2: o[d] = sum_mm e[mm]*m[mm,d] — wave h covers 25 rows, all
        // 25 row-words preloaded, p broadcast from LDS.
        {
            int c = tid & 63, h = tid >> 6;
            int mm0 = h * 25;
            unsigned pv[25];
#pragma unroll
            for (int k = 0; k < 25; ++k)
                pv[k] = mb[(mm0 + k) * (DD / 2) + c];
            float ax = 0.f, ay = 0.f;
#pragma unroll
            for (int k = 0; k < 25; ++k) {
                float p = p_s[mm0 + k];
                ax = fmaf(p, bflo(pv[k]), ax);
                ay = fmaf(p, bfhi(pv[k]), ay);
            }
            o_part[h][2 * c] = ax;
            o_part[h][2 * c + 1] = ay;
        }
        __syncthreads();
        // Phase 3: u'[d] = tanh( Hw[d,:] . u + inv * o[d] )
        float u_new = 0.f;
        if (tid < DD) {
            float o = 0.f;
#pragma unroll
            for (int h = 0; h < 8; ++h) o += o_part[h][tid];
            float acc = o * red_s;
            const float4* hrow = (const float4*)(Hw + tid * DD);
            const float4* u4 = (const float4*)u_s;
#pragma unroll 8
            for (int j = 0; j < DD / 4; ++j) {
                float4 hv = hrow[j];
                float4 uv = u4[j];
                acc += hv.x * uv.x + hv.y * uv.y + hv.z * uv.z + hv.w * uv.w;
            }
            u_new = tanhf(acc);
        }
        __syncthreads();
        if (tid < DD) u_s[tid] = u_new;
        __syncthreads();
    }
    if (tid < DD) uT[tid * BB + b] = u_s[tid];
}

// logits[b,c] = u[b,:] . cand_sum[c,:]. Block = 128 batches x 64 cands,
// 256 threads; thread = 4-batch x 8-cand register tile; k-major LDS cand tile.
__global__ __launch_bounds__(256) void k_logits(const float* __restrict__ uT,
                                                const float* __restrict__ cs,
                                                float* __restrict__ out) {
    __shared__ float c_s[DD][LCT + 4];  // 34.8 KB
    int c0 = blockIdx.x * LCT;
    int tid = threadIdx.x;
    {
        int c = tid >> 2, l = tid & 3;  // c 0..63, l = k-quarter
        int row = c0 + c;
        if (row >= NCC) row = NCC - 1;
        const float4* rp = (const float4*)(cs + (size_t)row * DD);
#pragma unroll
        for (int i = 0; i < 8; ++i) {
            int k = (l << 5) + (i << 2);
            float4 v = rp[(l << 3) + i];
            c_s[k][c] = v.x;
            c_s[k + 1][c] = v.y;
            c_s[k + 2][c] = v.z;
            c_s[k + 3][c] = v.w;
        }
    }
    __syncthreads();
    int tx = tid & 31, ty = tid >> 5;  // tx: 4 batches, ty: 8 cands
    const float* cb = &c_s[0][ty << 3];
    const float4* up = (const float4*)(uT + (tx << 2));
    float acc[4][8];
#pragma unroll
    for (int i = 0; i < 4; ++i)
#pragma unroll
        for (int j = 0; j < 8; ++j) acc[i][j] = 0.f;
#pragma unroll 4
    for (int k = 0; k < DD; ++k) {
        float4 uv = up[k * (BB / 4)];
        float4 ca = *(const float4*)(cb + k * (LCT + 4));
        float4 cc = *(const float4*)(cb + k * (LCT + 4) + 4);
        float uu[4] = {uv.x, uv.y, uv.z, uv.w};
        float cv[8] = {ca.x, ca.y, ca.z, ca.w, cc.x, cc.y, cc.z, cc.w};
#pragma unroll
        for (int i = 0; i < 4; ++i)
#pragma unroll
            for (int j = 0; j < 8; ++j) acc[i][j] = fmaf(uu[i], cv[j], acc[i][j]);
    }
    if (c0 + (ty << 3) < NCC) {  // 8-chunks; NCC % 8 == 0
#pragma unroll
        for (int i = 0; i < 4; ++i) {
            float* orow = out + (size_t)((tx << 2) + i) * NCC + c0 + (ty << 3);
            ((float4*)orow)[0] = make_float4(acc[i][0], acc[i][1], acc[i][2], acc[i][3]);
            ((float4*)orow)[1] = make_float4(acc[i][4], acc[i][5], acc[i][6], acc[i][7]);
        }
    }
}

extern "C" void kernel_launch(void* const* d_in, const int* in_sizes, int n_in,
                              void* d_out, int out_size, void* d_ws, size_t ws_size,
                              hipStream_t stream) {
    const int* stories = (const int*)d_in[0];       // [128,200,20] tokens
    const int* queries = (const int*)d_in[1];       // [128,20]
    const int* cands   = (const int*)d_in[2];       // [10000,10]
    const float* A  = (const float*)d_in[3];        // f32 [100000,128]
    const float* W  = (const float*)d_in[4];        // f32 [100000,128]
    const float* Hw = (const float*)d_in[5];        // f32 [128,128]
    float* out = (float*)d_out;                     // f32 [128,10000]

    unsigned* m_ws = (unsigned*)d_ws;                             // 6.55 MB
    float* cand_ws = (float*)(m_ws + (size_t)BB * MM * (DD / 2)); // 5.12 MB
    float* u_ws = cand_ws + (size_t)NCC * DD;                     // 64 KB
    float* uT = u_ws + BB * DD;                                   // 64 KB

    k_gather<<<512, 512, 0, stream>>>(stories, queries, cands, A, W,
                                      m_ws, cand_ws, u_ws);
    k_hops<<<BB, 512, 0, stream>>>(m_ws, u_ws, Hw, uT);
    k_logits<<<(NCC + LCT - 1) / LCT, 256, 0, stream>>>(uT, cand_ws, out);
}

// Round 10
// 193.268 us; speedup vs baseline: 1.0640x; 1.0084x over previous
//
#include <hip/hip_runtime.h>
#include <math.h>

#define BB 128
#define MM 200
#define SS 20
#define DD 128
#define NCC 10000
#define CL 10
#define LCT 64

__device__ __forceinline__ unsigned pack_bf16(float a, float b) {
    unsigned ua = __float_as_uint(a), ub = __float_as_uint(b);
    ua += 0x7fff + ((ua >> 16) & 1);  // RNE; inputs finite
    ub += 0x7fff + ((ub >> 16) & 1);
    return (ua >> 16) | (ub & 0xffff0000u);
}
__device__ __forceinline__ float bflo(unsigned v) { return __uint_as_float(v << 16); }
__device__ __forceinline__ float bfhi(unsigned v) { return __uint_as_float(v & 0xffff0000u); }

// int64-vs-int32 detection from 8 broadcast words of queries (odd words are the
// all-zero high halves iff int64; for int32 they're tokens, P(zero)=1e-5 each).
__device__ __forceinline__ int detect_shift(const int* __restrict__ q) {
    int zc = 0;
#pragma unroll
    for (int i = 0; i < 8; ++i) zc += (q[2 * i + 1] == 0);
    return (zc >= 6) ? 1 : 0;
}

// All random gathers in one chip-wide dispatch (512 blocks x 512 threads).
// __launch_bounds__(512, 4): 4 waves/EU target (= the 2 blocks/CU we already
// achieve) lifts the VGPR cap 64 -> ~128 so the allocator can keep all 20
// float4 gathers in flight (R9: VGPR=36 build serialized them at 3.2 TB/s).
__global__ __launch_bounds__(512, 4) void k_gather(const int* __restrict__ stories,
                                                   const int* __restrict__ queries,
                                                   const int* __restrict__ cands,
                                                   const float* __restrict__ A,
                                                   const float* __restrict__ W,
                                                   unsigned* __restrict__ m_ws,
                                                   float* __restrict__ cand_ws,
                                                   float* __restrict__ u_ws) {
    int gid = blockIdx.x, tid = threadIdx.x;
    int shift = detect_shift(queries);
    int g = tid >> 5, l = tid & 31;

    // Stories: 50 rows per block (row = b*MM + mm), 16 groups x 32 lanes.
    int base = gid * 50;
#pragma unroll
    for (int r = 0; r < 4; ++r) {
        int rl = (r << 4) + g;
        if (rl < 50) {
            int row = base + rl;
            int toks[SS];
#pragma unroll
            for (int s = 0; s < SS; ++s)
                toks[s] = stories[((size_t)(row * SS + s)) << shift];
            float4 vv[SS];
#pragma unroll
            for (int s = 0; s < SS; ++s)
                vv[s] = ((const float4*)(A + (size_t)toks[s] * DD))[l];
            float4 acc = make_float4(0.f, 0.f, 0.f, 0.f);
#pragma unroll
            for (int s = 0; s < SS; ++s) {
                float msk = toks[s] ? 1.f : 0.f;  // padding row 0
                acc.x = fmaf(msk, vv[s].x, acc.x);
                acc.y = fmaf(msk, vv[s].y, acc.y);
                acc.z = fmaf(msk, vv[s].z, acc.z);
                acc.w = fmaf(msk, vv[s].w, acc.w);
            }
            uint2 o;
            o.x = pack_bf16(acc.x, acc.y);
            o.y = pack_bf16(acc.z, acc.w);
            ((uint2*)(m_ws + (size_t)row * (DD / 2)))[l] = o;
        }
    }
    // Candidates: 20 rows per block (f32 out, masked), 10 loads in flight.
#pragma unroll
    for (int r = 0; r < 2; ++r) {
        int rl = (r << 4) + g;
        int row = gid * 20 + rl;
        if (rl < 20 && row < NCC) {
            int toks[CL];
#pragma unroll
            for (int s = 0; s < CL; ++s)
                toks[s] = cands[((size_t)(row * CL + s)) << shift];
            float4 vv[CL];
#pragma unroll
            for (int s = 0; s < CL; ++s)
                vv[s] = ((const float4*)(W + (size_t)toks[s] * DD))[l];
            float4 acc = make_float4(0.f, 0.f, 0.f, 0.f);
#pragma unroll
            for (int s = 0; s < CL; ++s) {
                float msk = toks[s] ? 1.f : 0.f;
                acc.x = fmaf(msk, vv[s].x, acc.x);
                acc.y = fmaf(msk, vv[s].y, acc.y);
                acc.z = fmaf(msk, vv[s].z, acc.z);
                acc.w = fmaf(msk, vv[s].w, acc.w);
            }
            ((float4*)(cand_ws + (size_t)row * DD))[l] = acc;
        }
    }
    // Queries: block b < 128, 32 lanes, f32 sum (exact).
    if (gid < BB && tid < 32) {
        int toks[SS];
#pragma unroll
        for (int s = 0; s < SS; ++s)
            toks[s] = queries[((size_t)(gid * SS + s)) << shift];
        float4 vv[SS];
#pragma unroll
        for (int s = 0; s < SS; ++s)
            vv[s] = ((const float4*)(A + (size_t)toks[s] * DD))[tid];
        float4 acc = make_float4(0.f, 0.f, 0.f, 0.f);
#pragma unroll
        for (int s = 0; s < SS; ++s) {
            float msk = toks[s] ? 1.f : 0.f;
            acc.x = fmaf(msk, vv[s].x, acc.x);
            acc.y = fmaf(msk, vv[s].y, acc.y);
            acc.z = fmaf(msk, vv[s].z, acc.z);
            acc.w = fmaf(msk, vv[s].w, acc.w);
        }
        ((float4*)(u_ws + (size_t)gid * DD))[tid] = acc;
    }
}

// 3 fused hops, one block per batch, m read from L2-warm m_ws (coalesced
// 256B-per-row wave reads). Phase 1 runs 5 interleaved shuffle chains.
__global__ __launch_bounds__(512) void k_hops(const unsigned* __restrict__ m_ws,
                                              const float* __restrict__ u_ws,
                                              const float* __restrict__ Hw,
                                              float* __restrict__ uT) {
    __shared__ float u_s[DD];
    __shared__ float p_s[MM];
    __shared__ float o_part[8][DD];
    __shared__ float red_s;
    int b = blockIdx.x, tid = threadIdx.x;
    int wave = tid >> 6, lane = tid & 63;
    const unsigned* mb = m_ws + (size_t)b * MM * (DD / 2);

    if (tid < DD) u_s[tid] = u_ws[b * DD + tid];
    __syncthreads();

    for (int hop = 0; hop < 3; ++hop) {
        // Phase 1: p[mm] = m[mm,:] . u — wave per 25 rows, 5 rows per pass
        // (5 independent loads + 5 interleaved 6-level shuffle reductions).
        {
            float2 uu = ((const float2*)u_s)[lane];
#pragma unroll
            for (int i = 0; i < 5; ++i) {
                int mm0 = wave * 25 + i * 5;
                unsigned pv[5];
#pragma unroll
                for (int k = 0; k < 5; ++k)
                    pv[k] = mb[(mm0 + k) * (DD / 2) + lane];
                float d[5];
#pragma unroll
                for (int k = 0; k < 5; ++k)
                    d[k] = bflo(pv[k]) * uu.x + bfhi(pv[k]) * uu.y;
#pragma unroll
                for (int off = 32; off; off >>= 1)
#pragma unroll
                    for (int k = 0; k < 5; ++k) d[k] += __shfl_down(d[k], off);
                if (lane == 0) {
#pragma unroll
                    for (int k = 0; k < 5; ++k) p_s[mm0 + k] = d[k];
                }
            }
        }
        __syncthreads();
        // Softmax over 200 (wave 0; 1/sum deferred to phase 3)
        if (tid < 64) {
            float v0 = p_s[tid], v1 = p_s[tid + 64], v2 = p_s[tid + 128];
            float v3 = (tid < 8) ? p_s[tid + 192] : -1e30f;
            float mx = fmaxf(fmaxf(v0, v1), fmaxf(v2, v3));
            for (int off = 32; off; off >>= 1) mx = fmaxf(mx, __shfl_down(mx, off));
            mx = __shfl(mx, 0);
            float e0 = __expf(v0 - mx), e1 = __expf(v1 - mx), e2 = __expf(v2 - mx);
            float e3 = (tid < 8) ? __expf(v3 - mx) : 0.f;
            float sm = e0 + e1 + e2 + e3;
            for (int off = 32; off; off >>= 1) sm += __shfl_down(sm, off);
            p_s[tid] = e0;
            p_s[tid + 64] = e1;
            p_s[tid + 128] = e2;
            if (tid < 8) p_s[tid + 192] = e3;
            if (tid == 0) red_s = 1.f / __shfl(sm, 0);
        }
        __syncthreads();
        // Phase 2: o[d] = sum_mm e[mm]*m[mm,d] — wave h covers 25 rows, all
        // 25 row-words preloaded, p broadcast from LDS.
        {
            int c = tid & 63, h = tid >> 6;
            int mm0 = h * 25;
            unsigned pv[25];
#pragma unroll
            for (int k = 0; k < 25; ++k)
                pv[k] = mb[(mm0 + k) * (DD / 2) + c];
            float ax = 0.f, ay = 0.f;
#pragma unroll
            for (int k = 0; k < 25; ++k) {
                float p = p_s[mm0 + k];
                ax = fmaf(p, bflo(pv[k]), ax);
                ay = fmaf(p, bfhi(pv[k]), ay);
            }
            o_part[h][2 * c] = ax;
            o_part[h][2 * c + 1] = ay;
        }
        __syncthreads();
        // Phase 3: u'[d] = tanh( Hw[d,:] . u + inv * o[d] )
        float u_new = 0.f;
        if (tid < DD) {
            float o = 0.f;
#pragma unroll
            for (int h = 0; h < 8; ++h) o += o_part[h][tid];
            float acc = o * red_s;
            const float4* hrow = (const float4*)(Hw + tid * DD);
            const float4* u4 = (const float4*)u_s;
#pragma unroll 8
            for (int j = 0; j < DD / 4; ++j) {
                float4 hv = hrow[j];
                float4 uv = u4[j];
                acc += hv.x * uv.x + hv.y * uv.y + hv.z * uv.z + hv.w * uv.w;
            }
            u_new = tanhf(acc);
        }
        __syncthreads();
        if (tid < DD) u_s[tid] = u_new;
        __syncthreads();
    }
    if (tid < DD) uT[tid * BB + b] = u_s[tid];
}

// logits[b,c] = u[b,:] . cand_sum[c,:]. Block = 128 batches x 64 cands,
// 256 threads; thread = 4-batch x 8-cand register tile; k-major LDS cand tile.
__global__ __launch_bounds__(256) void k_logits(const float* __restrict__ uT,
                                                const float* __restrict__ cs,
                                                float* __restrict__ out) {
    __shared__ float c_s[DD][LCT + 4];  // 34.8 KB
    int c0 = blockIdx.x * LCT;
    int tid = threadIdx.x;
    {
        int c = tid >> 2, l = tid & 3;  // c 0..63, l = k-quarter
        int row = c0 + c;
        if (row >= NCC) row = NCC - 1;
        const float4* rp = (const float4*)(cs + (size_t)row * DD);
#pragma unroll
        for (int i = 0; i < 8; ++i) {
            int k = (l << 5) + (i << 2);
            float4 v = rp[(l << 3) + i];
            c_s[k][c] = v.x;
            c_s[k + 1][c] = v.y;
            c_s[k + 2][c] = v.z;
            c_s[k + 3][c] = v.w;
        }
    }
    __syncthreads();
    int tx = tid & 31, ty = tid >> 5;  // tx: 4 batches, ty: 8 cands
    const float* cb = &c_s[0][ty << 3];
    const float4* up = (const float4*)(uT + (tx << 2));
    float acc[4][8];
#pragma unroll
    for (int i = 0; i < 4; ++i)
#pragma unroll
        for (int j = 0; j < 8; ++j) acc[i][j] = 0.f;
#pragma unroll 4
    for (int k = 0; k < DD; ++k) {
        float4 uv = up[k * (BB / 4)];
        float4 ca = *(const float4*)(cb + k * (LCT + 4));
        float4 cc = *(const float4*)(cb + k * (LCT + 4) + 4);
        float uu[4] = {uv.x, uv.y, uv.z, uv.w};
        float cv[8] = {ca.x, ca.y, ca.z, ca.w, cc.x, cc.y, cc.z, cc.w};
#pragma unroll
        for (int i = 0; i < 4; ++i)
#pragma unroll
            for (int j = 0; j < 8; ++j) acc[i][j] = fmaf(uu[i], cv[j], acc[i][j]);
    }
    if (c0 + (ty << 3) < NCC) {  // 8-chunks; NCC % 8 == 0
#pragma unroll
        for (int i = 0; i < 4; ++i) {
            float* orow = out + (size_t)((tx << 2) + i) * NCC + c0 + (ty << 3);
            ((float4*)orow)[0] = make_float4(acc[i][0], acc[i][1], acc[i][2], acc[i][3]);
            ((float4*)orow)[1] = make_float4(acc[i][4], acc[i][5], acc[i][6], acc[i][7]);
        }
    }
}

extern "C" void kernel_launch(void* const* d_in, const int* in_sizes, int n_in,
                              void* d_out, int out_size, void* d_ws, size_t ws_size,
                              hipStream_t stream) {
    const int* stories = (const int*)d_in[0];       // [128,200,20] tokens
    const int* queries = (const int*)d_in[1];       // [128,20]
    const int* cands   = (const int*)d_in[2];       // [10000,10]
    const float* A  = (const float*)d_in[3];        // f32 [100000,128]
    const float* W  = (const float*)d_in[4];        // f32 [100000,128]
    const float* Hw = (const float*)d_in[5];        // f32 [128,128]
    float* out = (float*)d_out;                     // f32 [128,10000]

    unsigned* m_ws = (unsigned*)d_ws;                             // 6.55 MB
    float* cand_ws = (float*)(m_ws + (size_t)BB * MM * (DD / 2)); // 5.12 MB
    float* u_ws = cand_ws + (size_t)NCC * DD;                     // 64 KB
    float* uT = u_ws + BB * DD;                                   // 64 KB

    k_gather<<<512, 512, 0, stream>>>(stories, queries, cands, A, W,
                                      m_ws, cand_ws, u_ws);
    k_hops<<<BB, 512, 0, stream>>>(m_ws, u_ws, Hw, uT);
    k_logits<<<(NCC + LCT - 1) / LCT, 256, 0, stream>>>(uT, cand_ws, out);
}

// Round 11
// 191.001 us; speedup vs baseline: 1.0766x; 1.0119x over previous
//
#include <hip/hip_runtime.h>
#include <math.h>

#define BB 128
#define MM 200
#define SS 20
#define DD 128
#define NCC 10000
#define CL 10
#define LCT 64

// k_gather grid segmentation (16 rows per 512-thread block, 32 lanes/row)
#define SBLK 1600                // story rows: 1600*16 = 25600
#define CBLK 625                 // cand rows: 625*16 = 10000
#define QBLK 8                   // query rows: 8*16 = 128
#define GBLK (SBLK + CBLK + QBLK)

__device__ __forceinline__ unsigned pack_bf16(float a, float b) {
    unsigned ua = __float_as_uint(a), ub = __float_as_uint(b);
    ua += 0x7fff + ((ua >> 16) & 1);  // RNE; inputs finite
    ub += 0x7fff + ((ub >> 16) & 1);
    return (ua >> 16) | (ub & 0xffff0000u);
}
__device__ __forceinline__ float bflo(unsigned v) { return __uint_as_float(v << 16); }
__device__ __forceinline__ float bfhi(unsigned v) { return __uint_as_float(v & 0xffff0000u); }

// int64-vs-int32 detection from 8 broadcast words of queries (odd words are the
// all-zero high halves iff int64; for int32 they're tokens, P(zero)=1e-5 each).
__device__ __forceinline__ int detect_shift(const int* __restrict__ q) {
    int zc = 0;
#pragma unroll
    for (int i = 0; i < 8; ++i) zc += (q[2 * i + 1] == 0);
    return (zc >= 6) ? 1 : 0;
}

// Flat gather: ONE row per 32-lane group, no per-thread row loop. 2233 blocks
// (~18k waves) give the full 32-waves/CU residency plus a deep queue — TLP
// hides gather latency since the compiler refuses ILP (VGPR pinned ~36,
// R9/R10: explicit load arrays and __launch_bounds__ were both no-ops).
__global__ __launch_bounds__(512) void k_gather(const int* __restrict__ stories,
                                                const int* __restrict__ queries,
                                                const int* __restrict__ cands,
                                                const float* __restrict__ A,
                                                const float* __restrict__ W,
                                                unsigned* __restrict__ m_ws,
                                                float* __restrict__ cand_ws,
                                                float* __restrict__ u_ws) {
    int gid = blockIdx.x, tid = threadIdx.x;
    int shift = detect_shift(queries);
    int g = tid >> 5, l = tid & 31;

    if (gid < SBLK) {
        // Stories: row = b*MM + mm; bf16-packed output.
        int row = (gid << 4) + g;
        int toks[SS];
#pragma unroll
        for (int s = 0; s < SS; ++s)
            toks[s] = stories[((size_t)(row * SS + s)) << shift];
        float4 acc = make_float4(0.f, 0.f, 0.f, 0.f);
#pragma unroll
        for (int s = 0; s < SS; ++s) {
            float4 v = ((const float4*)(A + (size_t)toks[s] * DD))[l];
            float msk = toks[s] ? 1.f : 0.f;  // padding row 0
            acc.x = fmaf(msk, v.x, acc.x);
            acc.y = fmaf(msk, v.y, acc.y);
            acc.z = fmaf(msk, v.z, acc.z);
            acc.w = fmaf(msk, v.w, acc.w);
        }
        uint2 o;
        o.x = pack_bf16(acc.x, acc.y);
        o.y = pack_bf16(acc.z, acc.w);
        ((uint2*)(m_ws + (size_t)row * (DD / 2)))[l] = o;
    } else if (gid < SBLK + CBLK) {
        // Candidates: f32 out, masked.
        int row = ((gid - SBLK) << 4) + g;
        int toks[CL];
#pragma unroll
        for (int s = 0; s < CL; ++s)
            toks[s] = cands[((size_t)(row * CL + s)) << shift];
        float4 acc = make_float4(0.f, 0.f, 0.f, 0.f);
#pragma unroll
        for (int s = 0; s < CL; ++s) {
            float4 v = ((const float4*)(W + (size_t)toks[s] * DD))[l];
            float msk = toks[s] ? 1.f : 0.f;
            acc.x = fmaf(msk, v.x, acc.x);
            acc.y = fmaf(msk, v.y, acc.y);
            acc.z = fmaf(msk, v.z, acc.z);
            acc.w = fmaf(msk, v.w, acc.w);
        }
        ((float4*)(cand_ws + (size_t)row * DD))[l] = acc;
    } else {
        // Queries: f32 sum (exact).
        int b = ((gid - SBLK - CBLK) << 4) + g;
        int toks[SS];
#pragma unroll
        for (int s = 0; s < SS; ++s)
            toks[s] = queries[((size_t)(b * SS + s)) << shift];
        float4 acc = make_float4(0.f, 0.f, 0.f, 0.f);
#pragma unroll
        for (int s = 0; s < SS; ++s) {
            float4 v = ((const float4*)(A + (size_t)toks[s] * DD))[l];
            float msk = toks[s] ? 1.f : 0.f;
            acc.x = fmaf(msk, v.x, acc.x);
            acc.y = fmaf(msk, v.y, acc.y);
            acc.z = fmaf(msk, v.z, acc.z);
            acc.w = fmaf(msk, v.w, acc.w);
        }
        ((float4*)(u_ws + (size_t)b * DD))[l] = acc;
    }
}

// 3 fused hops, one block per batch, m read from L2-warm m_ws (coalesced
// 256B-per-row wave reads). Phase 1 runs 5 interleaved shuffle chains.
__global__ __launch_bounds__(512) void k_hops(const unsigned* __restrict__ m_ws,
                                              const float* __restrict__ u_ws,
                                              const float* __restrict__ Hw,
                                              float* __restrict__ uT) {
    __shared__ float u_s[DD];
    __shared__ float p_s[MM];
    __shared__ float o_part[8][DD];
    __shared__ float red_s;
    int b = blockIdx.x, tid = threadIdx.x;
    int wave = tid >> 6, lane = tid & 63;
    const unsigned* mb = m_ws + (size_t)b * MM * (DD / 2);

    if (tid < DD) u_s[tid] = u_ws[b * DD + tid];
    __syncthreads();

    for (int hop = 0; hop < 3; ++hop) {
        // Phase 1: p[mm] = m[mm,:] . u — wave per 25 rows, 5 rows per pass
        // (5 independent loads + 5 interleaved 6-level shuffle reductions).
        {
            float2 uu = ((const float2*)u_s)[lane];
#pragma unroll
            for (int i = 0; i < 5; ++i) {
                int mm0 = wave * 25 + i * 5;
                unsigned pv[5];
#pragma unroll
                for (int k = 0; k < 5; ++k)
                    pv[k] = mb[(mm0 + k) * (DD / 2) + lane];
                float d[5];
#pragma unroll
                for (int k = 0; k < 5; ++k)
                    d[k] = bflo(pv[k]) * uu.x + bfhi(pv[k]) * uu.y;
#pragma unroll
                for (int off = 32; off; off >>= 1)
#pragma unroll
                    for (int k = 0; k < 5; ++k) d[k] += __shfl_down(d[k], off);
                if (lane == 0) {
#pragma unroll
                    for (int k = 0; k < 5; ++k) p_s[mm0 + k] = d[k];
                }
            }
        }
        __syncthreads();
        // Softmax over 200 (wave 0; 1/sum deferred to phase 3)
        if (tid < 64) {
            float v0 = p_s[tid], v1 = p_s[tid + 64], v2 = p_s[tid + 128];
            float v3 = (tid < 8) ? p_s[tid + 192] : -1e30f;
            float mx = fmaxf(fmaxf(v0, v1), fmaxf(v2, v3));
            for (int off = 32; off; off >>= 1) mx = fmaxf(mx, __shfl_down(mx, off));
            mx = __shfl(mx, 0);
            float e0 = __expf(v0 - mx), e1 = __expf(v1 - mx), e2 = __expf(v2 - mx);
            float e3 = (tid < 8) ? __expf(v3 - mx) : 0.f;
            float sm = e0 + e1 + e2 + e3;
            for (int off = 32; off; off >>= 1) sm += __shfl_down(sm, off);
            p_s[tid] = e0;
            p_s[tid + 64] = e1;
            p_s[tid + 128] = e2;
            if (tid < 8) p_s[tid + 192] = e3;
            if (tid == 0) red_s = 1.f / __shfl(sm, 0);
        }
        __syncthreads();
        // Phase 2: o[d] = sum_mm e[mm]*m[mm,d] — wave h covers 25 rows, all
        // 25 row-words preloaded, p broadcast from LDS.
        {
            int c = tid & 63, h = tid >> 6;
            int mm0 = h * 25;
            unsigned pv[25];
#pragma unroll
            for (int k = 0; k < 25; ++k)
                pv[k] = mb[(mm0 + k) * (DD / 2) + c];
            float ax = 0.f, ay = 0.f;
#pragma unroll
            for (int k = 0; k < 25; ++k) {
                float p = p_s[mm0 + k];
                ax = fmaf(p, bflo(pv[k]), ax);
                ay = fmaf(p, bfhi(pv[k]), ay);
            }
            o_part[h][2 * c] = ax;
            o_part[h][2 * c + 1] = ay;
        }
        __syncthreads();
        // Phase 3: u'[d] = tanh( Hw[d,:] . u + inv * o[d] )
        float u_new = 0.f;
        if (tid < DD) {
            float o = 0.f;
#pragma unroll
            for (int h = 0; h < 8; ++h) o += o_part[h][tid];
            float acc = o * red_s;
            const float4* hrow = (const float4*)(Hw + tid * DD);
            const float4* u4 = (const float4*)u_s;
#pragma unroll 8
            for (int j = 0; j < DD / 4; ++j) {
                float4 hv = hrow[j];
                float4 uv = u4[j];
                acc += hv.x * uv.x + hv.y * uv.y + hv.z * uv.z + hv.w * uv.w;
            }
            u_new = tanhf(acc);
        }
        __syncthreads();
        if (tid < DD) u_s[tid] = u_new;
        __syncthreads();
    }
    if (tid < DD) uT[tid * BB + b] = u_s[tid];
}

// logits[b,c] = u[b,:] . cand_sum[c,:]. Block = 128 batches x 64 cands,
// 256 threads; thread = 4-batch x 8-cand register tile; k-major LDS cand tile.
__global__ __launch_bounds__(256) void k_logits(const float* __restrict__ uT,
                                                const float* __restrict__ cs,
                                                float* __restrict__ out) {
    __shared__ float c_s[DD][LCT + 4];  // 34.8 KB
    int c0 = blockIdx.x * LCT;
    int tid = threadIdx.x;
    {
        int c = tid >> 2, l = tid & 3;  // c 0..63, l = k-quarter
        int row = c0 + c;
        if (row >= NCC) row = NCC - 1;
        const float4* rp = (const float4*)(cs + (size_t)row * DD);
#pragma unroll
        for (int i = 0; i < 8; ++i) {
            int k = (l << 5) + (i << 2);
            float4 v = rp[(l << 3) + i];
            c_s[k][c] = v.x;
            c_s[k + 1][c] = v.y;
            c_s[k + 2][c] = v.z;
            c_s[k + 3][c] = v.w;
        }
    }
    __syncthreads();
    int tx = tid & 31, ty = tid >> 5;  // tx: 4 batches, ty: 8 cands
    const float* cb = &c_s[0][ty << 3];
    const float4* up = (const float4*)(uT + (tx << 2));
    float acc[4][8];
#pragma unroll
    for (int i = 0; i < 4; ++i)
#pragma unroll
        for (int j = 0; j < 8; ++j) acc[i][j] = 0.f;
#pragma unroll 4
    for (int k = 0; k < DD; ++k) {
        float4 uv = up[k * (BB / 4)];
        float4 ca = *(const float4*)(cb + k * (LCT + 4));
        float4 cc = *(const float4*)(cb + k * (LCT + 4) + 4);
        float uu[4] = {uv.x, uv.y, uv.z, uv.w};
        float cv[8] = {ca.x, ca.y, ca.z, ca.w, cc.x, cc.y, cc.z, cc.w};
#pragma unroll
        for (int i = 0; i < 4; ++i)
#pragma unroll
            for (int j = 0; j < 8; ++j) acc[i][j] = fmaf(uu[i], cv[j], acc[i][j]);
    }
    if (c0 + (ty << 3) < NCC) {  // 8-chunks; NCC % 8 == 0
#pragma unroll
        for (int i = 0; i < 4; ++i) {
            float* orow = out + (size_t)((tx << 2) + i) * NCC + c0 + (ty << 3);
            ((float4*)orow)[0] = make_float4(acc[i][0], acc[i][1], acc[i][2], acc[i][3]);
            ((float4*)orow)[1] = make_float4(acc[i][4], acc[i][5], acc[i][6], acc[i][7]);
        }
    }
}

extern "C" void kernel_launch(void* const* d_in, const int* in_sizes, int n_in,
                              void* d_out, int out_size, void* d_ws, size_t ws_size,
                              hipStream_t stream) {
    const int* stories = (const int*)d_in[0];       // [128,200,20] tokens
    const int* queries = (const int*)d_in[1];       // [128,20]
    const int* cands   = (const int*)d_in[2];       // [10000,10]
    const float* A  = (const float*)d_in[3];        // f32 [100000,128]
    const float* W  = (const float*)d_in[4];        // f32 [100000,128]
    const float* Hw = (const float*)d_in[5];        // f32 [128,128]
    float* out = (float*)d_out;                     // f32 [128,10000]

    unsigned* m_ws = (unsigned*)d_ws;                             // 6.55 MB
    float* cand_ws = (float*)(m_ws + (size_t)BB * MM * (DD / 2)); // 5.12 MB
    float* u_ws = cand_ws + (size_t)NCC * DD;                     // 64 KB
    float* uT = u_ws + BB * DD;                                   // 64 KB

    k_gather<<<GBLK, 512, 0, stream>>>(stories, queries, cands, A, W,
                                       m_ws, cand_ws, u_ws);
    k_hops<<<BB, 512, 0, stream>>>(m_ws, u_ws, Hw, uT);
    k_logits<<<(NCC + LCT - 1) / LCT, 256, 0, stream>>>(uT, cand_ws, out);
}